// Round 7
// baseline (670.608 us; speedup 1.0000x reference)
//
#include <hip/hip_runtime.h>

static constexpr int NN = 50000;
static constexpr int NE = 1000000;

typedef short bf16x8 __attribute__((ext_vector_type(8)));
typedef float f32x4 __attribute__((ext_vector_type(4)));
typedef unsigned short u16x2 __attribute__((ext_vector_type(2)));

__device__ inline float bf2f_raw(unsigned short u) {
    return __uint_as_float(((unsigned int)u) << 16);
}
__device__ inline unsigned short f2bf(float f) {
    unsigned int u = __float_as_uint(f);
    u += 0x7fffu + ((u >> 16) & 1u);
    return (unsigned short)(u >> 16);
}
// sortable-bf16: monotone bijection so unsigned order == float order (max commutes, bit-exact)
__device__ inline unsigned short f2bfs(float f) {
    unsigned short b = f2bf(f);
    return (b & 0x8000u) ? (unsigned short)(~b) : (unsigned short)(b | 0x8000u);
}
__device__ inline float unsrt2f(unsigned short v) {
    unsigned short b = (v & 0x8000u) ? (unsigned short)(v ^ 0x8000u)
                                     : (unsigned short)(~v);
    return bf2f_raw(b);  // transformed 0 -> bf16 NaN -> fmaxf(NaN,0)=0 (empty row)
}
__device__ inline unsigned int pkmax(unsigned int a, unsigned int b) {
    u16x2 r = __builtin_elementwise_max(__builtin_bit_cast(u16x2, a),
                                        __builtin_bit_cast(u16x2, b));
    return __builtin_bit_cast(unsigned int, r);
}
__device__ inline uint4 pkmax4(uint4 a, uint4 b) {
    a.x = pkmax(a.x, b.x); a.y = pkmax(a.y, b.y);
    a.z = pkmax(a.z, b.z); a.w = pkmax(a.w, b.w);
    return a;
}
__device__ inline unsigned int pack2(float f0, float f1) {
    return (unsigned int)f2bf(f0) | ((unsigned int)f2bf(f1) << 16);
}
// a: plain bf16 pair; t: sortable-bf16 pair (max result). out = relu(a + t) packed.
__device__ inline unsigned int addrelu2t(unsigned int a, unsigned int t) {
    float t0 = unsrt2f((unsigned short)(t & 0xffffu));
    float t1 = unsrt2f((unsigned short)(t >> 16));
    float f0 = fmaxf(bf2f_raw((unsigned short)(a & 0xffffu)) + t0, 0.f);
    float f1 = fmaxf(bf2f_raw((unsigned short)(a >> 16)) + t1, 0.f);
    return pack2(f0, f1);
}

// ---------------- merged setup: a1 + out-init + deg-zero + cursor-zero + weight prep --------

__global__ void setup_kernel(const float* __restrict__ x, const float* __restrict__ W1,
                             const float* __restrict__ b1, const float* __restrict__ b5,
                             const float* __restrict__ W2, const float* __restrict__ W3,
                             const float* __restrict__ W4,
                             unsigned short* __restrict__ a1buf, float* __restrict__ out,
                             int* __restrict__ deg, int* __restrict__ cursor,
                             unsigned short* __restrict__ Bt2,
                             unsigned short* __restrict__ Bt3,
                             unsigned short* __restrict__ W4t) {
    int t = blockIdx.x * blockDim.x + threadIdx.x;
    if (t < NN * 64) {
        // conv1 a-half only: a1 = x@(Wt-Wb)+b1 (W1 is [6][64]); s1 recomputed per edge
        int i = t >> 6, c = t & 63;
        float x0 = x[i * 3 + 0], x1 = x[i * 3 + 1], x2 = x[i * 3 + 2];
        float v = x0 * (W1[c] - W1[192 + c]) + x1 * (W1[64 + c] - W1[256 + c]) +
                  x2 * (W1[128 + c] - W1[320 + c]) + b1[c];
        a1buf[t] = f2bf(v);
        return;
    }
    t -= NN * 64;
    if (t < NN * 3) { out[t] = x[t] + b5[t % 3]; return; }
    t -= NN * 3;
    if (t < NN) { deg[t] = 0; return; }
    t -= NN;
    if (t < NN) { cursor[t] = 0; return; }
    t -= NN;
    if (t < 8192) {  // W2 split (64x128): [c<128] = (Wt-Wb)^T (a-part), [128+c] = Wb^T (s-part)
        int k = t / 128, c = t % 128;
        float wt = W2[k * 128 + c];
        float wb = W2[(64 + k) * 128 + c];
        Bt2[c * 64 + k] = f2bf(wt - wb);
        Bt2[(128 + c) * 64 + k] = f2bf(wb);
        return;
    }
    t -= 8192;
    if (t < 65536) {  // W3 split (128x512): [c<512] = (Wt-Wb)^T (a-part), [512+c] = Wb^T (s-part)
        int k = t / 512, c = t % 512;
        float wt = W3[k * 512 + c];
        float wb = W3[(128 + k) * 512 + c];
        Bt3[c * 128 + k] = f2bf(wt - wb);
        Bt3[(512 + c) * 128 + k] = f2bf(wb);
        return;
    }
    t -= 65536;
    if (t < 131072) {  // W4 transpose (512x256)
        int k = t / 256, n = t % 256;
        W4t[n * 512 + k] = f2bf(W4[k * 256 + n]);
    }
}

// ---------------- CSR build ----------------

__global__ void hist_kernel(const int* __restrict__ dst, int* __restrict__ deg) {
    int e = blockIdx.x * blockDim.x + threadIdx.x;
    if (e < NE) atomicAdd(&deg[dst[e]], 1);
}

// single-block scan, register-resident
__global__ __launch_bounds__(1024) void scan_kernel(const int* __restrict__ deg,
                                                    int* __restrict__ rowstart) {
    __shared__ int wave_sums[16];
    constexpr int CH = (NN + 1023) / 1024;  // 49
    int tid = threadIdx.x;
    int lane = tid & 63;
    int wave = tid >> 6;
    int base = tid * CH;
    int vals[CH];
    int sum = 0;
    #pragma unroll
    for (int i = 0; i < CH; ++i) {
        int idx = base + i;
        vals[i] = (idx < NN) ? deg[idx] : 0;
        sum += vals[i];
    }
    int x = sum;
    #pragma unroll
    for (int off = 1; off < 64; off <<= 1) {
        int y = __shfl_up(x, off);
        if (lane >= off) x += y;
    }
    if (lane == 63) wave_sums[wave] = x;
    __syncthreads();
    if (wave == 0 && lane < 16) {
        int s = wave_sums[lane];
        #pragma unroll
        for (int off = 1; off < 16; off <<= 1) {
            int y = __shfl_up(s, off);
            if (lane >= off) s += y;
        }
        wave_sums[lane] = s;
    }
    __syncthreads();
    int run = (wave ? wave_sums[wave - 1] : 0) + x - sum;
    #pragma unroll
    for (int i = 0; i < CH; ++i) {
        int idx = base + i;
        if (idx < NN) rowstart[idx] = run;
        run += vals[i];
    }
    if (tid == 1023) rowstart[NN] = run;
}

__global__ void scatter_kernel(const int* __restrict__ src, const int* __restrict__ dst,
                               const int* __restrict__ rowstart, int* __restrict__ cursor,
                               int* __restrict__ csr) {
    int e = blockIdx.x * blockDim.x + threadIdx.x;
    if (e < NE) {
        int d = dst[e];
        int pos = atomicAdd(&cursor[d], 1);
        csr[rowstart[d] + pos] = src[e];
    }
}

// ---------------- conv1: recompute s1 per edge from raw x (600KB slab, L2-resident) -------
// One wave per node; lane owns channel c. Per 16-edge group: lanes e*4+comp load x[j_e][comp]
// (one wave-load covers 16 edges), broadcast via shfl, 3 FMA per (edge, channel).
// s rounded to bf16 before max -> identical values to the old materialized path.

__global__ __launch_bounds__(256) void conv1_kernel(
    const float* __restrict__ x, const int* __restrict__ rowstart,
    const int* __restrict__ csr, const float* __restrict__ W1,
    const unsigned short* __restrict__ a1buf, unsigned short* __restrict__ x1) {
    int wid = (blockIdx.x * 256 + threadIdx.x) >> 6;
    int lane = threadIdx.x & 63;
    if (wid >= NN) return;
    int e0 = __builtin_amdgcn_readfirstlane(rowstart[wid]);
    int e1 = __builtin_amdgcn_readfirstlane(rowstart[wid + 1]);
    int ne = e1 - e0;
    float wa = W1[192 + lane], wb = W1[256 + lane], wc = W1[320 + lane];
    float m = -INFINITY;
    if (ne > 0) {
        int last = ne - 1;
        int eidx = lane >> 2, comp = lane & 3;
        for (int e = 0; e < ne; e += 16) {
            int idx = e + eidx; if (idx > last) idx = last;
            int j = csr[e0 + idx];
            float v = 0.f;
            if (comp < 3) v = x[(size_t)j * 3 + comp];
            #pragma unroll
            for (int k = 0; k < 16; ++k) {
                float x0 = __shfl(v, k * 4 + 0);
                float x1v = __shfl(v, k * 4 + 1);
                float x2v = __shfl(v, k * 4 + 2);
                float s = x0 * wa + x1v * wb + x2v * wc;
                s = bf2f_raw(f2bf(s));  // replicate old bf16 rounding (monotone)
                m = fmaxf(m, s);
            }
        }
    }
    float a = bf2f_raw(a1buf[(size_t)wid * 64 + lane]);
    x1[(size_t)wid * 64 + lane] = f2bf(fmaxf(a + m, 0.f));
}

// ---------------- fused conv2: a2 MFMA + on-the-fly s2 per edge-batch -> x2 ----------------
// Block = 16 nodes (4 waves x 4 nodes). No s2 materialization (GEMM2 removed):
// gather x1[j] rows (128B, HALF the old s2 traffic) into per-wave LDS edge tile,
// compute s2 batch = E(16x64)@Wb2 via the SAME K=64 MFMA chain (bit-identical f32),
// round->col-max->running max in LDS (sortable u16). Combine with a2, store x2.

__global__ __launch_bounds__(256) void ef128_x1_kernel(
    const unsigned short* __restrict__ x1, const int* __restrict__ rowstart,
    const int* __restrict__ csr, const unsigned short* __restrict__ Bt2,
    const float* __restrict__ b2, unsigned short* __restrict__ x2) {
    __shared__ __align__(16) unsigned short x1t[16][72];
    __shared__ __align__(16) unsigned short A2[16][136];
    __shared__ __align__(16) unsigned short M[16][136];   // sortable u16 running col-max
    __shared__ __align__(16) unsigned short E[4][16][72]; // per-wave edge tiles
    int tid = threadIdx.x;
    int wave = tid >> 6, lane = tid & 63;
    int quad = lane >> 4, l16 = lane & 15;
    int tilebase = blockIdx.x * 16;

    // p0: stage x1 tile + zero M
    if (tid < 128) {
        int row = tid >> 3, seg = tid & 7;
        uint4 v = *(const uint4*)(x1 + (size_t)(tilebase + row) * 64 + seg * 8);
        *(uint4*)&x1t[row][seg * 8] = v;
    }
    #pragma unroll
    for (int idx = tid; idx < 16 * 64; idx += 256) {
        int row = idx >> 6, c2 = idx & 63;
        *(unsigned int*)&M[row][c2 * 2] = 0u;
    }
    __syncthreads();

    // p1: a2 = x1t @ Bt2a + b2 (wave covers cols [wave*32,+32)) -> A2 bf16
    {
        int colbase = wave * 32;
        f32x4 acc[2] = {};
        #pragma unroll
        for (int kc = 0; kc < 2; ++kc) {
            bf16x8 afr = *(const bf16x8*)&x1t[l16][kc * 32 + quad * 8];
            #pragma unroll
            for (int nt = 0; nt < 2; ++nt) {
                int col = colbase + nt * 16 + l16;
                bf16x8 bfr = *(const bf16x8*)&Bt2[(size_t)col * 64 + kc * 32 + quad * 8];
                acc[nt] = __builtin_amdgcn_mfma_f32_16x16x32_bf16(afr, bfr, acc[nt], 0, 0, 0);
            }
        }
        #pragma unroll
        for (int nt = 0; nt < 2; ++nt) {
            int col = colbase + nt * 16 + l16;
            float bv = b2[col];
            #pragma unroll
            for (int r = 0; r < 4; ++r)
                A2[quad * 4 + r][col] = f2bf(acc[nt][r] + bv);
        }
    }

    // p2: per node: batches of 16 edges (clamped duplicates are idempotent under max)
    for (int i = 0; i < 4; ++i) {
        int nl = wave * 4 + i;
        int node = tilebase + nl;
        int e0 = __builtin_amdgcn_readfirstlane(rowstart[node]);
        int e1 = __builtin_amdgcn_readfirstlane(rowstart[node + 1]);
        int ne = e1 - e0;
        if (ne <= 0) continue;
        int last = ne - 1;
        for (int e = 0; e < ne; e += 16) {
            // gather 16 x1 rows: 2 edges per load pass, 8 passes (dword/lane)
            int cj[8];
            #pragma unroll
            for (int sub = 0; sub < 8; ++sub) {
                int ee = sub * 2 + (lane >> 5);
                int idx = e + ee; if (idx > last) idx = last;
                cj[sub] = csr[e0 + idx];
            }
            unsigned int g[8];
            #pragma unroll
            for (int sub = 0; sub < 8; ++sub)
                g[sub] = *(const unsigned int*)(x1 + (size_t)cj[sub] * 64 + (lane & 31) * 2);
            #pragma unroll
            for (int sub = 0; sub < 8; ++sub)
                *(unsigned int*)&E[wave][sub * 2 + (lane >> 5)][(lane & 31) * 2] = g[sub];
            // s2 batch MFMA (identical K=64 chain), N in 2 halves to cap VGPR
            #pragma unroll
            for (int half = 0; half < 2; ++half) {
                f32x4 acc[4] = {};
                #pragma unroll
                for (int kc = 0; kc < 2; ++kc) {
                    bf16x8 afr = *(const bf16x8*)&E[wave][l16][kc * 32 + quad * 8];
                    #pragma unroll
                    for (int nt = 0; nt < 4; ++nt) {
                        int col = half * 64 + nt * 16 + l16;
                        bf16x8 bfr = *(const bf16x8*)&Bt2[(size_t)(128 + col) * 64 + kc * 32 + quad * 8];
                        acc[nt] = __builtin_amdgcn_mfma_f32_16x16x32_bf16(afr, bfr, acc[nt], 0, 0, 0);
                    }
                }
                #pragma unroll
                for (int nt = 0; nt < 4; ++nt) {
                    float cm = fmaxf(fmaxf(acc[nt][0], acc[nt][1]),
                                     fmaxf(acc[nt][2], acc[nt][3]));
                    cm = fmaxf(cm, __shfl_xor(cm, 16));
                    cm = fmaxf(cm, __shfl_xor(cm, 32));
                    if (lane < 16) {
                        unsigned short sv = f2bfs(cm);
                        int col = half * 64 + nt * 16 + l16;
                        unsigned short old = M[nl][col];
                        if (sv > old) M[nl][col] = sv;
                    }
                }
            }
        }
    }
    __syncthreads();

    // p3: x2 = relu(a2 + max s2)
    #pragma unroll
    for (int i = 0; i < 4; ++i) {
        int row = wave * 4 + i;
        unsigned int av = *(const unsigned int*)&A2[row][lane * 2];
        unsigned int mv = *(const unsigned int*)&M[row][lane * 2];
        *(unsigned int*)(x2 + (size_t)(tilebase + row) * 128 + lane * 2) =
            addrelu2t(av, mv);
    }
}

// ---------------- fused ef512: a3 MFMA (first) + s3 gather + h4-GEMM + W5 ----------------
// R5 phase order (measured best duty), single X buffer (16.9KB LDS):
// p0: stage x2 tile into X[.][0:128); snapshot A-frags. p1: a3 MFMA -> X (all 512 cols).
// p2: gather s3-max (uint4/lane, groups of 8, clamped). p3: combine in place.
// p4: h = relu(X@W4t+b4); out += h@W5 (atomic).

__global__ __launch_bounds__(256) void ef512_w5_kernel(
    const unsigned short* __restrict__ s3, const unsigned short* __restrict__ x2,
    const int* __restrict__ rowstart, const int* __restrict__ csr,
    const unsigned short* __restrict__ Bt3a, const float* __restrict__ b3,
    const unsigned short* __restrict__ W4t,
    const float* __restrict__ b4, const float* __restrict__ W5,
    float* __restrict__ out) {
    __shared__ __align__(16) unsigned short X[16][520];
    int tid = threadIdx.x;
    int wave = tid >> 6, lane = tid & 63;
    int quad = lane >> 4, l16 = lane & 15;
    int tilebase = blockIdx.x * 16;

    // p0: stage x2 tile into X cols [0,128)
    {
        int row = tid >> 4, seg = tid & 15;
        uint4 v = *(const uint4*)(x2 + (size_t)(tilebase + row) * 128 + seg * 8);
        *(uint4*)&X[row][seg * 8] = v;
    }
    __syncthreads();
    bf16x8 afr[4];
    #pragma unroll
    for (int kc = 0; kc < 4; ++kc)
        afr[kc] = *(const bf16x8*)&X[l16][kc * 32 + quad * 8];
    __syncthreads();

    // p1: a3 = x2 @ Bt3a + b3 (wave covers cols [wave*128,+128)) -> X bf16
    {
        int colbase = wave * 128;
        f32x4 acc3[8] = {};
        #pragma unroll
        for (int kc = 0; kc < 4; ++kc) {
            #pragma unroll
            for (int nt = 0; nt < 8; ++nt) {
                int col = colbase + nt * 16 + l16;
                bf16x8 bfr = *(const bf16x8*)&Bt3a[(size_t)col * 128 + kc * 32 + quad * 8];
                acc3[nt] = __builtin_amdgcn_mfma_f32_16x16x32_bf16(afr[kc], bfr, acc3[nt], 0, 0, 0);
            }
        }
        #pragma unroll
        for (int nt = 0; nt < 8; ++nt) {
            int col = colbase + nt * 16 + l16;
            float bv = b3[col];
            #pragma unroll
            for (int r = 0; r < 4; ++r)
                X[quad * 4 + r][col] = f2bf(acc3[nt][r] + bv);
        }
    }

    // p2: gather s3-max for nodes wave*4 .. wave*4+3
    uint4 m[4];
    for (int i = 0; i < 4; ++i) {
        int node = tilebase + wave * 4 + i;
        int e0 = __builtin_amdgcn_readfirstlane(rowstart[node]);
        int e1 = __builtin_amdgcn_readfirstlane(rowstart[node + 1]);
        int nedge = e1 - e0;
        uint4 mA = make_uint4(0u, 0u, 0u, 0u), mB = make_uint4(0u, 0u, 0u, 0u);
        if (nedge > 0) {
            int last = nedge - 1;
            for (int e = 0; e < nedge; e += 8) {
                int jj[8];
                #pragma unroll
                for (int k = 0; k < 8; ++k) {
                    int idx = e + k; if (idx > last) idx = last;
                    jj[k] = __builtin_amdgcn_readfirstlane(csr[e0 + idx]);
                }
                uint4 v[8];
                #pragma unroll
                for (int k = 0; k < 8; ++k)
                    v[k] = *(const uint4*)(s3 + (size_t)jj[k] * 512 + lane * 8);
                #pragma unroll
                for (int k = 0; k < 8; ++k) {
                    if (k & 1) mB = pkmax4(mB, v[k]);
                    else       mA = pkmax4(mA, v[k]);
                }
            }
        }
        m[i] = pkmax4(mA, mB);
    }
    __syncthreads();

    // p3: combine in place (wave owns rows wave*4..+3)
    #pragma unroll
    for (int i = 0; i < 4; ++i) {
        int row = wave * 4 + i;
        uint4 av = *(const uint4*)&X[row][lane * 8];
        uint4 o;
        o.x = addrelu2t(av.x, m[i].x);
        o.y = addrelu2t(av.y, m[i].y);
        o.z = addrelu2t(av.z, m[i].z);
        o.w = addrelu2t(av.w, m[i].w);
        *(uint4*)&X[row][lane * 8] = o;
    }
    __syncthreads();

    // p4: h cols [wave*64, +64); epilogue W5
    int colbase = wave * 64;
    f32x4 acc4[4] = {};
    for (int kc = 0; kc < 16; ++kc) {
        bf16x8 a4 = *(const bf16x8*)&X[l16][kc * 32 + quad * 8];
        #pragma unroll
        for (int nt = 0; nt < 4; ++nt) {
            int col = colbase + nt * 16 + l16;
            bf16x8 bfr = *(const bf16x8*)&W4t[(size_t)col * 512 + kc * 32 + quad * 8];
            acc4[nt] = __builtin_amdgcn_mfma_f32_16x16x32_bf16(a4, bfr, acc4[nt], 0, 0, 0);
        }
    }
    float b4v[4], w5r[4][3];
    #pragma unroll
    for (int nt = 0; nt < 4; ++nt) {
        int col = colbase + nt * 16 + l16;
        b4v[nt] = b4[col];
        w5r[nt][0] = W5[col * 3 + 0];
        w5r[nt][1] = W5[col * 3 + 1];
        w5r[nt][2] = W5[col * 3 + 2];
    }
    #pragma unroll
    for (int r = 0; r < 4; ++r) {
        int row = tilebase + quad * 4 + r;
        float p0 = 0.f, p1 = 0.f, p2 = 0.f;
        #pragma unroll
        for (int nt = 0; nt < 4; ++nt) {
            float h = fmaxf(acc4[nt][r] + b4v[nt], 0.f);
            p0 += h * w5r[nt][0];
            p1 += h * w5r[nt][1];
            p2 += h * w5r[nt][2];
        }
        #pragma unroll
        for (int mm = 8; mm; mm >>= 1) {
            p0 += __shfl_xor(p0, mm);
            p1 += __shfl_xor(p1, mm);
            p2 += __shfl_xor(p2, mm);
        }
        if (l16 == 0) {
            atomicAdd(&out[row * 3 + 0], p0);
            atomicAdd(&out[row * 3 + 1], p1);
            atomicAdd(&out[row * 3 + 2], p2);
        }
    }
}

// ---------------- N-loop MFMA GEMM: A staged in LDS ONCE, loop over N-tiles ----------------
// cols >= bias_n are the s-half: stored sortable-transformed for pk_max gathers.

template<int K, int NT>
__global__ __launch_bounds__(256) void mfma_gemm_nloop_kernel(
    const unsigned short* __restrict__ A, const unsigned short* __restrict__ Bt,
    const float* __restrict__ bias, int bias_n,
    unsigned short* __restrict__ C, int M) {
    constexpr int KC = K / 32;
    constexpr int N = NT * 128;
    __shared__ __align__(16) unsigned short Asl[KC][128 * 40];
    __shared__ __align__(16) unsigned short Bsl[128 * 40];
    int tid = threadIdx.x;
    int mbase = blockIdx.x * 128;
    int wave = tid >> 6, lane = tid & 63;
    int wm = (wave >> 1) * 64, wn = (wave & 1) * 64;
    int quad = lane >> 4, l16 = lane & 15;

    #pragma unroll
    for (int c = tid; c < KC * 512; c += 256) {
        int kc = c >> 9, rem = c & 511;
        int r = rem >> 2, kk = (rem & 3) * 8;
        uint4 va = make_uint4(0u, 0u, 0u, 0u);
        int gr = mbase + r;
        if (gr < M) va = *(const uint4*)&A[(size_t)gr * K + kc * 32 + kk];
        *(uint4*)&Asl[kc][r * 40 + kk] = va;
    }

    for (int nt = 0; nt < NT; ++nt) {
        int nbase = nt * 128;
        f32x4 acc[4][4] = {};
        for (int kc = 0; kc < KC; ++kc) {
            __syncthreads();
            #pragma unroll
            for (int h = 0; h < 2; ++h) {
                int c = tid + h * 256;
                int r = c >> 2, kk = (c & 3) * 8;
                uint4 vb = *(const uint4*)&Bt[(size_t)(nbase + r) * K + kc * 32 + kk];
                *(uint4*)&Bsl[r * 40 + kk] = vb;
            }
            __syncthreads();
            bf16x8 af[4], bfr[4];
            #pragma unroll
            for (int tt = 0; tt < 4; ++tt) {
                af[tt]  = *(const bf16x8*)&Asl[kc][(wm + tt * 16 + l16) * 40 + quad * 8];
                bfr[tt] = *(const bf16x8*)&Bsl[(wn + tt * 16 + l16) * 40 + quad * 8];
            }
            #pragma unroll
            for (int mt = 0; mt < 4; ++mt)
                #pragma unroll
                for (int ntt = 0; ntt < 4; ++ntt)
                    acc[mt][ntt] = __builtin_amdgcn_mfma_f32_16x16x32_bf16(
                        af[mt], bfr[ntt], acc[mt][ntt], 0, 0, 0);
        }
        #pragma unroll
        for (int mt = 0; mt < 4; ++mt) {
            #pragma unroll
            for (int r = 0; r < 4; ++r) {
                int row = mbase + wm + mt * 16 + quad * 4 + r;
                if (row >= M) continue;
                #pragma unroll
                for (int ntt = 0; ntt < 4; ++ntt) {
                    int col = nbase + wn + ntt * 16 + l16;
                    float v = acc[mt][ntt][r];
                    unsigned short o;
                    if (col < bias_n) o = f2bf(v + bias[col]);
                    else o = f2bfs(v);
                    C[(size_t)row * N + col] = o;
                }
            }
        }
    }
}

__global__ void fallback_copy_kernel(const float* __restrict__ x, float* __restrict__ out) {
    int t = blockIdx.x * blockDim.x + threadIdx.x;
    if (t < NN * 3) out[t] = x[t];
}

// ---------------- launcher ----------------

extern "C" void kernel_launch(void* const* d_in, const int* in_sizes, int n_in,
                              void* d_out, int out_size, void* d_ws, size_t ws_size,
                              hipStream_t stream) {
    const float* x  = (const float*)d_in[0];
    const int*   ei = (const int*)d_in[1];
    const float* W1 = (const float*)d_in[2];
    const float* b1 = (const float*)d_in[3];
    const float* W2 = (const float*)d_in[4];
    const float* b2 = (const float*)d_in[5];
    const float* W3 = (const float*)d_in[6];
    const float* b3 = (const float*)d_in[7];
    const float* W4 = (const float*)d_in[8];
    const float* b4 = (const float*)d_in[9];
    const float* W5 = (const float*)d_in[10];
    const float* b5 = (const float*)d_in[11];
    float* out = (float*)d_out;

    char* p = (char*)d_ws;
    auto alloc = [&](size_t bytes) -> void* {
        void* r = (void*)p;
        p += (bytes + 255) & ~(size_t)255;
        return r;
    };
    int* deg      = (int*)alloc((size_t)NN * 4);
    int* rowstart = (int*)alloc((size_t)(NN + 1) * 4);
    int* cursor   = (int*)alloc((size_t)NN * 4);
    int* csr      = (int*)alloc((size_t)NE * 4);
    unsigned short* Bt2 = (unsigned short*)alloc(256 * 64 * 2);
    unsigned short* Bt3 = (unsigned short*)alloc(1024 * 128 * 2);
    unsigned short* W4t = (unsigned short*)alloc(256 * 512 * 2);
    unsigned short* a1 = (unsigned short*)alloc((size_t)NN * 64 * 2);
    unsigned short* x1 = (unsigned short*)alloc((size_t)NN * 64 * 2);
    unsigned short* x2 = (unsigned short*)alloc((size_t)NN * 128 * 2);
    unsigned short* s3 = (unsigned short*)alloc((size_t)NN * 512 * 2);
    size_t need = (size_t)(p - (char*)d_ws);
    if (ws_size < need) {
        fallback_copy_kernel<<<(NN * 3 + 255) / 256, 256, 0, stream>>>(x, out);
        return;
    }

    const int* src = ei;        // edge_index[0]
    const int* dst = ei + NE;   // edge_index[1]

    // merged setup (one dispatch)
    constexpr int SETUP_T = NN * 64 + NN * 3 + NN + NN + 8192 + 65536 + 131072;
    setup_kernel<<<(SETUP_T + 255) / 256, 256, 0, stream>>>(
        x, W1, b1, b5, W2, W3, W4, a1, out, deg, cursor, Bt2, Bt3, W4t);

    // CSR by dst (graph static across all 3 convs)
    hist_kernel<<<(NE + 255) / 256, 256, 0, stream>>>(dst, deg);
    scan_kernel<<<1, 1024, 0, stream>>>(deg, rowstart);
    scatter_kernel<<<(NE + 255) / 256, 256, 0, stream>>>(src, dst, rowstart, cursor, csr);

    // conv1: s1 recomputed per edge from raw x (L2-resident slab)
    conv1_kernel<<<12500, 256, 0, stream>>>(x, rowstart, csr, W1, a1, x1);

    // conv2: fused a2 MFMA + on-the-fly s2 (x1 gather, no s2 materialization)
    ef128_x1_kernel<<<NN / 16, 256, 0, stream>>>(x1, rowstart, csr, Bt2, b2, x2);

    // conv3 s-half ONLY: s3 = x2 @ Wb3 (sortable); a3 computed in fused kernel
    mfma_gemm_nloop_kernel<128, 4><<<391, 256, 0, stream>>>(
        x2, Bt3 + 512 * 128, b3, 0, s3, NN);

    // fused: a3 in-kernel MFMA + s3 gather-max + h=relu(X@W4+b4) + out += h@W5
    ef512_w5_kernel<<<NN / 16, 256, 0, stream>>>(
        s3, x2, rowstart, csr, Bt3, b3, W4t, b4, W5, out);
}

// Round 8
// 565.894 us; speedup vs baseline: 1.1850x; 1.1850x over previous
//
#include <hip/hip_runtime.h>

static constexpr int NN = 50000;
static constexpr int NE = 1000000;

typedef short bf16x8 __attribute__((ext_vector_type(8)));
typedef float f32x4 __attribute__((ext_vector_type(4)));
typedef unsigned short u16x2 __attribute__((ext_vector_type(2)));

__device__ inline float bf2f_raw(unsigned short u) {
    return __uint_as_float(((unsigned int)u) << 16);
}
__device__ inline unsigned short f2bf(float f) {
    unsigned int u = __float_as_uint(f);
    u += 0x7fffu + ((u >> 16) & 1u);
    return (unsigned short)(u >> 16);
}
// sortable-bf16: monotone bijection so unsigned order == float order (max commutes, bit-exact)
__device__ inline unsigned short f2bfs(float f) {
    unsigned short b = f2bf(f);
    return (b & 0x8000u) ? (unsigned short)(~b) : (unsigned short)(b | 0x8000u);
}
__device__ inline float unsrt2f(unsigned short v) {
    unsigned short b = (v & 0x8000u) ? (unsigned short)(v ^ 0x8000u)
                                     : (unsigned short)(~v);
    return bf2f_raw(b);  // transformed 0 -> bf16 NaN -> fmaxf(NaN,0)=0 (empty row)
}
__device__ inline unsigned int pkmax(unsigned int a, unsigned int b) {
    u16x2 r = __builtin_elementwise_max(__builtin_bit_cast(u16x2, a),
                                        __builtin_bit_cast(u16x2, b));
    return __builtin_bit_cast(unsigned int, r);
}
__device__ inline uint4 pkmax4(uint4 a, uint4 b) {
    a.x = pkmax(a.x, b.x); a.y = pkmax(a.y, b.y);
    a.z = pkmax(a.z, b.z); a.w = pkmax(a.w, b.w);
    return a;
}
__device__ inline unsigned int pack2(float f0, float f1) {
    return (unsigned int)f2bf(f0) | ((unsigned int)f2bf(f1) << 16);
}
// a: plain bf16 pair; t: sortable-bf16 pair (max result). out = relu(a + t) packed.
__device__ inline unsigned int addrelu2t(unsigned int a, unsigned int t) {
    float t0 = unsrt2f((unsigned short)(t & 0xffffu));
    float t1 = unsrt2f((unsigned short)(t >> 16));
    float f0 = fmaxf(bf2f_raw((unsigned short)(a & 0xffffu)) + t0, 0.f);
    float f1 = fmaxf(bf2f_raw((unsigned short)(a >> 16)) + t1, 0.f);
    return pack2(f0, f1);
}

// ---------------- merged setup: conv1_as + out-init + deg-zero + cursor-zero + weight prep --------

__global__ void setup_kernel(const float* __restrict__ x, const float* __restrict__ W1,
                             const float* __restrict__ b1, const float* __restrict__ b5,
                             const float* __restrict__ W2, const float* __restrict__ W3,
                             const float* __restrict__ W4,
                             unsigned short* __restrict__ as1, float* __restrict__ out,
                             int* __restrict__ deg, int* __restrict__ cursor,
                             unsigned short* __restrict__ Bt2,
                             unsigned short* __restrict__ Bt3,
                             unsigned short* __restrict__ W4t) {
    int t = blockIdx.x * blockDim.x + threadIdx.x;
    if (t < NN * 128) {
        // conv1: as1[i] = [a1(64) | s1(64)], a = x@(Wt-Wb)+b1, s = x@Wb (W1 is [6][64])
        int i = t >> 7, c = t & 127;
        float x0 = x[i * 3 + 0], x1 = x[i * 3 + 1], x2 = x[i * 3 + 2];
        if (c < 64) {
            float v = x0 * (W1[c] - W1[192 + c]) + x1 * (W1[64 + c] - W1[256 + c]) +
                      x2 * (W1[128 + c] - W1[320 + c]) + b1[c];
            as1[t] = f2bf(v);
        } else {
            int cs = c - 64;
            float v = x0 * W1[192 + cs] + x1 * W1[256 + cs] + x2 * W1[320 + cs];
            as1[t] = f2bfs(v);
        }
        return;
    }
    t -= NN * 128;
    if (t < NN * 3) { out[t] = x[t] + b5[t % 3]; return; }
    t -= NN * 3;
    if (t < NN) { deg[t] = 0; return; }
    t -= NN;
    if (t < NN) { cursor[t] = 0; return; }
    t -= NN;
    if (t < 8192) {  // W2 split (64x128): [c<128] = (Wt-Wb)^T (a-part), [128+c] = Wb^T (s-part)
        int k = t / 128, c = t % 128;
        float wt = W2[k * 128 + c];
        float wb = W2[(64 + k) * 128 + c];
        Bt2[c * 64 + k] = f2bf(wt - wb);
        Bt2[(128 + c) * 64 + k] = f2bf(wb);
        return;
    }
    t -= 8192;
    if (t < 65536) {  // W3 split (128x512): [c<512] = (Wt-Wb)^T (a-part), [512+c] = Wb^T (s-part)
        int k = t / 512, c = t % 512;
        float wt = W3[k * 512 + c];
        float wb = W3[(128 + k) * 512 + c];
        Bt3[c * 128 + k] = f2bf(wt - wb);
        Bt3[(512 + c) * 128 + k] = f2bf(wb);
        return;
    }
    t -= 65536;
    if (t < 131072) {  // W4 transpose (512x256)
        int k = t / 256, n = t % 256;
        W4t[n * 512 + k] = f2bf(W4[k * 256 + n]);
    }
}

// ---------------- CSR build ----------------

__global__ void hist_kernel(const int* __restrict__ dst, int* __restrict__ deg) {
    int e = blockIdx.x * blockDim.x + threadIdx.x;
    if (e < NE) atomicAdd(&deg[dst[e]], 1);
}

// single-block scan, register-resident
__global__ __launch_bounds__(1024) void scan_kernel(const int* __restrict__ deg,
                                                    int* __restrict__ rowstart) {
    __shared__ int wave_sums[16];
    constexpr int CH = (NN + 1023) / 1024;  // 49
    int tid = threadIdx.x;
    int lane = tid & 63;
    int wave = tid >> 6;
    int base = tid * CH;
    int vals[CH];
    int sum = 0;
    #pragma unroll
    for (int i = 0; i < CH; ++i) {
        int idx = base + i;
        vals[i] = (idx < NN) ? deg[idx] : 0;
        sum += vals[i];
    }
    int x = sum;
    #pragma unroll
    for (int off = 1; off < 64; off <<= 1) {
        int y = __shfl_up(x, off);
        if (lane >= off) x += y;
    }
    if (lane == 63) wave_sums[wave] = x;
    __syncthreads();
    if (wave == 0 && lane < 16) {
        int s = wave_sums[lane];
        #pragma unroll
        for (int off = 1; off < 16; off <<= 1) {
            int y = __shfl_up(s, off);
            if (lane >= off) s += y;
        }
        wave_sums[lane] = s;
    }
    __syncthreads();
    int run = (wave ? wave_sums[wave - 1] : 0) + x - sum;
    #pragma unroll
    for (int i = 0; i < CH; ++i) {
        int idx = base + i;
        if (idx < NN) rowstart[idx] = run;
        run += vals[i];
    }
    if (tid == 1023) rowstart[NN] = run;
}

__global__ void scatter_kernel(const int* __restrict__ src, const int* __restrict__ dst,
                               const int* __restrict__ rowstart, int* __restrict__ cursor,
                               int* __restrict__ csr) {
    int e = blockIdx.x * blockDim.x + threadIdx.x;
    if (e < NE) {
        int d = dst[e];
        int pos = atomicAdd(&cursor[d], 1);
        csr[rowstart[d] + pos] = src[e];
    }
}

// ---------------- conv1 fused edge-max + epilogue (C=64, as rows [a(64)|s(64)]) ----------------
// One wave per node. Edge index j is wave-uniform: readfirstlane(csr[..]) -> saddr loads.
// Groups of 16 edges, indices clamped (max idempotent) -> 16 independent loads in flight.

__global__ __launch_bounds__(256) void edge_fused_conv1_kernel(
    const unsigned short* __restrict__ as, const int* __restrict__ rowstart,
    const int* __restrict__ csr, unsigned short* __restrict__ x1) {
    int wid = (blockIdx.x * 256 + threadIdx.x) >> 6;
    int lane = threadIdx.x & 63;
    if (wid >= NN) return;
    int e0 = __builtin_amdgcn_readfirstlane(rowstart[wid]);
    int e1 = __builtin_amdgcn_readfirstlane(rowstart[wid + 1]);
    int nedge = e1 - e0;
    unsigned int mA = 0u, mB = 0u;
    if (nedge > 0) {
        int last = nedge - 1;
        for (int e = 0; e < nedge; e += 16) {
            int jj[16];
            #pragma unroll
            for (int k = 0; k < 16; ++k) {
                int idx = e + k; if (idx > last) idx = last;
                jj[k] = __builtin_amdgcn_readfirstlane(csr[e0 + idx]);
            }
            unsigned int v[16];
            #pragma unroll
            for (int k = 0; k < 16; ++k)
                v[k] = *(const unsigned short*)(as + (size_t)jj[k] * 128 + 64 + lane);
            #pragma unroll
            for (int k = 0; k < 16; ++k) {
                if (k & 1) mB = mB > v[k] ? mB : v[k];
                else       mA = mA > v[k] ? mA : v[k];
            }
        }
    }
    unsigned int m = mA > mB ? mA : mB;
    unsigned short a = as[(size_t)wid * 128 + lane];
    float t = unsrt2f((unsigned short)m);
    float f = fmaxf(bf2f_raw(a) + t, 0.f);
    x1[(size_t)wid * 64 + lane] = f2bf(f);
}

// ---------------- fused conv2: a2 MFMA (global A-frags, no staging) + s2 gather -> x2 ------
// Block = 16 nodes (4 waves x 4 nodes). ZERO barriers before/during the gather:
// a2 A-fragments are loaded directly from global x1 (same values the staged tile gave,
// bit-identical MFMA chain). Order: a2 MFMA -> A2 LDS, gather s2, sync, combine+store.

__global__ __launch_bounds__(256) void ef128_a2_kernel(
    const unsigned short* __restrict__ s2, const unsigned short* __restrict__ x1,
    const int* __restrict__ rowstart, const int* __restrict__ csr,
    const unsigned short* __restrict__ Bt2a, const float* __restrict__ b2,
    unsigned short* __restrict__ x2) {
    __shared__ __align__(16) unsigned short A2[16][136];
    int tid = threadIdx.x;
    int wave = tid >> 6, lane = tid & 63;
    int quad = lane >> 4, l16 = lane & 15;
    int tilebase = blockIdx.x * 16;

    // a2 A-frags direct from global (row = tilebase+l16, ch = kc*32+quad*8)
    bf16x8 afr[2];
    #pragma unroll
    for (int kc = 0; kc < 2; ++kc)
        afr[kc] = *(const bf16x8*)&x1[(size_t)(tilebase + l16) * 64 + kc * 32 + quad * 8];

    // a2 = x1 @ Bt2a + b2 (wave covers cols [wave*32,+32)) -> A2 bf16
    {
        int colbase = wave * 32;
        f32x4 acc[2] = {};
        #pragma unroll
        for (int kc = 0; kc < 2; ++kc) {
            #pragma unroll
            for (int nt = 0; nt < 2; ++nt) {
                int col = colbase + nt * 16 + l16;
                bf16x8 bfr = *(const bf16x8*)&Bt2a[(size_t)col * 64 + kc * 32 + quad * 8];
                acc[nt] = __builtin_amdgcn_mfma_f32_16x16x32_bf16(afr[kc], bfr, acc[nt], 0, 0, 0);
            }
        }
        #pragma unroll
        for (int nt = 0; nt < 2; ++nt) {
            int col = colbase + nt * 16 + l16;
            float bv = b2[col];
            #pragma unroll
            for (int r = 0; r < 4; ++r)
                A2[quad * 4 + r][col] = f2bf(acc[nt][r] + bv);
        }
    }

    // gather s2-max for nodes wave*4 .. wave*4+3 (groups of 16, clamped)
    unsigned int m[4];
    for (int i = 0; i < 4; ++i) {
        int node = tilebase + wave * 4 + i;
        int e0 = __builtin_amdgcn_readfirstlane(rowstart[node]);
        int e1 = __builtin_amdgcn_readfirstlane(rowstart[node + 1]);
        int nedge = e1 - e0;
        unsigned int mA = 0u, mB = 0u;
        if (nedge > 0) {
            int last = nedge - 1;
            for (int e = 0; e < nedge; e += 16) {
                int jj[16];
                #pragma unroll
                for (int k = 0; k < 16; ++k) {
                    int idx = e + k; if (idx > last) idx = last;
                    jj[k] = __builtin_amdgcn_readfirstlane(csr[e0 + idx]);
                }
                unsigned int v[16];
                #pragma unroll
                for (int k = 0; k < 16; ++k)
                    v[k] = *(const unsigned int*)(s2 + (size_t)jj[k] * 128 + lane * 2);
                #pragma unroll
                for (int k = 0; k < 16; ++k) {
                    if (k & 1) mB = pkmax(mB, v[k]);
                    else       mA = pkmax(mA, v[k]);
                }
            }
        }
        m[i] = pkmax(mA, mB);
    }
    __syncthreads();

    // combine + store x2
    #pragma unroll
    for (int i = 0; i < 4; ++i) {
        int row = wave * 4 + i;
        unsigned int av = *(const unsigned int*)&A2[row][lane * 2];
        *(unsigned int*)(x2 + (size_t)(tilebase + row) * 128 + lane * 2) =
            addrelu2t(av, m[i]);
    }
}

// ---------------- fused ef512: a3 MFMA (global A-frags) + s3 gather + h4-GEMM + W5 ---------
// Block = 16 nodes (4 waves x 4 nodes). ZERO barriers before/during the gather:
// a3 A-frags loaded directly from global x2 (bit-identical to staged path).
// Order: a3 MFMA -> X, gather s3 (the ~100us/block phase, unimpeded), sync,
// combine in place, sync, h = relu(X@W4t+b4), out += h@W5 (atomic).

__global__ __launch_bounds__(256) void ef512_w5_kernel(
    const unsigned short* __restrict__ s3, const unsigned short* __restrict__ x2,
    const int* __restrict__ rowstart, const int* __restrict__ csr,
    const unsigned short* __restrict__ Bt3a, const float* __restrict__ b3,
    const unsigned short* __restrict__ W4t,
    const float* __restrict__ b4, const float* __restrict__ W5,
    float* __restrict__ out) {
    __shared__ __align__(16) unsigned short X[16][520];
    int tid = threadIdx.x;
    int wave = tid >> 6, lane = tid & 63;
    int quad = lane >> 4, l16 = lane & 15;
    int tilebase = blockIdx.x * 16;

    // a3 A-frags direct from global (row = tilebase+l16, ch = kc*32+quad*8)
    bf16x8 afr[4];
    #pragma unroll
    for (int kc = 0; kc < 4; ++kc)
        afr[kc] = *(const bf16x8*)&x2[(size_t)(tilebase + l16) * 128 + kc * 32 + quad * 8];

    // a3 = x2 @ Bt3a + b3 (wave covers cols [wave*128,+128)) -> X bf16
    {
        int colbase = wave * 128;
        f32x4 acc3[8] = {};
        #pragma unroll
        for (int kc = 0; kc < 4; ++kc) {
            #pragma unroll
            for (int nt = 0; nt < 8; ++nt) {
                int col = colbase + nt * 16 + l16;
                bf16x8 bfr = *(const bf16x8*)&Bt3a[(size_t)col * 128 + kc * 32 + quad * 8];
                acc3[nt] = __builtin_amdgcn_mfma_f32_16x16x32_bf16(afr[kc], bfr, acc3[nt], 0, 0, 0);
            }
        }
        #pragma unroll
        for (int nt = 0; nt < 8; ++nt) {
            int col = colbase + nt * 16 + l16;
            float bv = b3[col];
            #pragma unroll
            for (int r = 0; r < 4; ++r)
                X[quad * 4 + r][col] = f2bf(acc3[nt][r] + bv);
        }
    }

    // gather s3-max for nodes wave*4 .. wave*4+3 (groups of 8 uint4, clamped)
    uint4 m[4];
    for (int i = 0; i < 4; ++i) {
        int node = tilebase + wave * 4 + i;
        int e0 = __builtin_amdgcn_readfirstlane(rowstart[node]);
        int e1 = __builtin_amdgcn_readfirstlane(rowstart[node + 1]);
        int nedge = e1 - e0;
        uint4 mA = make_uint4(0u, 0u, 0u, 0u), mB = make_uint4(0u, 0u, 0u, 0u);
        if (nedge > 0) {
            int last = nedge - 1;
            for (int e = 0; e < nedge; e += 8) {
                int jj[8];
                #pragma unroll
                for (int k = 0; k < 8; ++k) {
                    int idx = e + k; if (idx > last) idx = last;
                    jj[k] = __builtin_amdgcn_readfirstlane(csr[e0 + idx]);
                }
                uint4 v[8];
                #pragma unroll
                for (int k = 0; k < 8; ++k)
                    v[k] = *(const uint4*)(s3 + (size_t)jj[k] * 512 + lane * 8);
                #pragma unroll
                for (int k = 0; k < 8; ++k) {
                    if (k & 1) mB = pkmax4(mB, v[k]);
                    else       mA = pkmax4(mA, v[k]);
                }
            }
        }
        m[i] = pkmax4(mA, mB);
    }
    __syncthreads();

    // combine in place (wave owns rows wave*4..+3)
    #pragma unroll
    for (int i = 0; i < 4; ++i) {
        int row = wave * 4 + i;
        uint4 av = *(const uint4*)&X[row][lane * 8];
        uint4 o;
        o.x = addrelu2t(av.x, m[i].x);
        o.y = addrelu2t(av.y, m[i].y);
        o.z = addrelu2t(av.z, m[i].z);
        o.w = addrelu2t(av.w, m[i].w);
        *(uint4*)&X[row][lane * 8] = o;
    }
    __syncthreads();

    // h cols [wave*64, +64); epilogue W5
    int colbase = wave * 64;
    f32x4 acc4[4] = {};
    for (int kc = 0; kc < 16; ++kc) {
        bf16x8 a4 = *(const bf16x8*)&X[l16][kc * 32 + quad * 8];
        #pragma unroll
        for (int nt = 0; nt < 4; ++nt) {
            int col = colbase + nt * 16 + l16;
            bf16x8 bfr = *(const bf16x8*)&W4t[(size_t)col * 512 + kc * 32 + quad * 8];
            acc4[nt] = __builtin_amdgcn_mfma_f32_16x16x32_bf16(a4, bfr, acc4[nt], 0, 0, 0);
        }
    }
    float b4v[4], w5r[4][3];
    #pragma unroll
    for (int nt = 0; nt < 4; ++nt) {
        int col = colbase + nt * 16 + l16;
        b4v[nt] = b4[col];
        w5r[nt][0] = W5[col * 3 + 0];
        w5r[nt][1] = W5[col * 3 + 1];
        w5r[nt][2] = W5[col * 3 + 2];
    }
    #pragma unroll
    for (int r = 0; r < 4; ++r) {
        int row = tilebase + quad * 4 + r;
        float p0 = 0.f, p1 = 0.f, p2 = 0.f;
        #pragma unroll
        for (int nt = 0; nt < 4; ++nt) {
            float h = fmaxf(acc4[nt][r] + b4v[nt], 0.f);
            p0 += h * w5r[nt][0];
            p1 += h * w5r[nt][1];
            p2 += h * w5r[nt][2];
        }
        #pragma unroll
        for (int mm = 8; mm; mm >>= 1) {
            p0 += __shfl_xor(p0, mm);
            p1 += __shfl_xor(p1, mm);
            p2 += __shfl_xor(p2, mm);
        }
        if (l16 == 0) {
            atomicAdd(&out[row * 3 + 0], p0);
            atomicAdd(&out[row * 3 + 1], p1);
            atomicAdd(&out[row * 3 + 2], p2);
        }
    }
}

// ---------------- N-loop MFMA GEMM: A staged in LDS ONCE, loop over N-tiles ----------------
// cols >= bias_n are the s-half: stored sortable-transformed for pk_max gathers.

template<int K, int NT>
__global__ __launch_bounds__(256) void mfma_gemm_nloop_kernel(
    const unsigned short* __restrict__ A, const unsigned short* __restrict__ Bt,
    const float* __restrict__ bias, int bias_n,
    unsigned short* __restrict__ C, int M) {
    constexpr int KC = K / 32;
    constexpr int N = NT * 128;
    __shared__ __align__(16) unsigned short Asl[KC][128 * 40];
    __shared__ __align__(16) unsigned short Bsl[128 * 40];
    int tid = threadIdx.x;
    int mbase = blockIdx.x * 128;
    int wave = tid >> 6, lane = tid & 63;
    int wm = (wave >> 1) * 64, wn = (wave & 1) * 64;
    int quad = lane >> 4, l16 = lane & 15;

    #pragma unroll
    for (int c = tid; c < KC * 512; c += 256) {
        int kc = c >> 9, rem = c & 511;
        int r = rem >> 2, kk = (rem & 3) * 8;
        uint4 va = make_uint4(0u, 0u, 0u, 0u);
        int gr = mbase + r;
        if (gr < M) va = *(const uint4*)&A[(size_t)gr * K + kc * 32 + kk];
        *(uint4*)&Asl[kc][r * 40 + kk] = va;
    }

    for (int nt = 0; nt < NT; ++nt) {
        int nbase = nt * 128;
        f32x4 acc[4][4] = {};
        for (int kc = 0; kc < KC; ++kc) {
            __syncthreads();
            #pragma unroll
            for (int h = 0; h < 2; ++h) {
                int c = tid + h * 256;
                int r = c >> 2, kk = (c & 3) * 8;
                uint4 vb = *(const uint4*)&Bt[(size_t)(nbase + r) * K + kc * 32 + kk];
                *(uint4*)&Bsl[r * 40 + kk] = vb;
            }
            __syncthreads();
            bf16x8 af[4], bfr[4];
            #pragma unroll
            for (int tt = 0; tt < 4; ++tt) {
                af[tt]  = *(const bf16x8*)&Asl[kc][(wm + tt * 16 + l16) * 40 + quad * 8];
                bfr[tt] = *(const bf16x8*)&Bsl[(wn + tt * 16 + l16) * 40 + quad * 8];
            }
            #pragma unroll
            for (int mt = 0; mt < 4; ++mt)
                #pragma unroll
                for (int ntt = 0; ntt < 4; ++ntt)
                    acc[mt][ntt] = __builtin_amdgcn_mfma_f32_16x16x32_bf16(
                        af[mt], bfr[ntt], acc[mt][ntt], 0, 0, 0);
        }
        #pragma unroll
        for (int mt = 0; mt < 4; ++mt) {
            #pragma unroll
            for (int r = 0; r < 4; ++r) {
                int row = mbase + wm + mt * 16 + quad * 4 + r;
                if (row >= M) continue;
                #pragma unroll
                for (int ntt = 0; ntt < 4; ++ntt) {
                    int col = nbase + wn + ntt * 16 + l16;
                    float v = acc[mt][ntt][r];
                    unsigned short o;
                    if (col < bias_n) o = f2bf(v + bias[col]);
                    else o = f2bfs(v);
                    C[(size_t)row * N + col] = o;
                }
            }
        }
    }
}

__global__ void fallback_copy_kernel(const float* __restrict__ x, float* __restrict__ out) {
    int t = blockIdx.x * blockDim.x + threadIdx.x;
    if (t < NN * 3) out[t] = x[t];
}

// ---------------- launcher ----------------

extern "C" void kernel_launch(void* const* d_in, const int* in_sizes, int n_in,
                              void* d_out, int out_size, void* d_ws, size_t ws_size,
                              hipStream_t stream) {
    const float* x  = (const float*)d_in[0];
    const int*   ei = (const int*)d_in[1];
    const float* W1 = (const float*)d_in[2];
    const float* b1 = (const float*)d_in[3];
    const float* W2 = (const float*)d_in[4];
    const float* b2 = (const float*)d_in[5];
    const float* W3 = (const float*)d_in[6];
    const float* b3 = (const float*)d_in[7];
    const float* W4 = (const float*)d_in[8];
    const float* b4 = (const float*)d_in[9];
    const float* W5 = (const float*)d_in[10];
    const float* b5 = (const float*)d_in[11];
    float* out = (float*)d_out;

    char* p = (char*)d_ws;
    auto alloc = [&](size_t bytes) -> void* {
        void* r = (void*)p;
        p += (bytes + 255) & ~(size_t)255;
        return r;
    };
    int* deg      = (int*)alloc((size_t)NN * 4);
    int* rowstart = (int*)alloc((size_t)(NN + 1) * 4);
    int* cursor   = (int*)alloc((size_t)NN * 4);
    int* csr      = (int*)alloc((size_t)NE * 4);
    unsigned short* Bt2 = (unsigned short*)alloc(256 * 64 * 2);
    unsigned short* Bt3 = (unsigned short*)alloc(1024 * 128 * 2);
    unsigned short* W4t = (unsigned short*)alloc(256 * 512 * 2);
    unsigned short* x1 = (unsigned short*)alloc((size_t)NN * 64 * 2);
    unsigned short* x2 = (unsigned short*)alloc((size_t)NN * 128 * 2);
    unsigned short* as_slab = (unsigned short*)alloc((size_t)NN * 512 * 2);  // as1/s2/s3
    size_t need = (size_t)(p - (char*)d_ws);
    if (ws_size < need) {
        fallback_copy_kernel<<<(NN * 3 + 255) / 256, 256, 0, stream>>>(x, out);
        return;
    }

    const int* src = ei;        // edge_index[0]
    const int* dst = ei + NE;   // edge_index[1]

    // merged setup (one dispatch)
    constexpr int SETUP_T = NN * 128 + NN * 3 + NN + NN + 8192 + 65536 + 131072;
    setup_kernel<<<(SETUP_T + 255) / 256, 256, 0, stream>>>(
        x, W1, b1, b5, W2, W3, W4, as_slab, out, deg, cursor, Bt2, Bt3, W4t);

    // CSR by dst (graph static across all 3 convs)
    hist_kernel<<<(NE + 255) / 256, 256, 0, stream>>>(dst, deg);
    scan_kernel<<<1, 1024, 0, stream>>>(deg, rowstart);
    scatter_kernel<<<(NE + 255) / 256, 256, 0, stream>>>(src, dst, rowstart, cursor, csr);

    // conv1: x1 = relu(a1 + max_j s1[j])
    edge_fused_conv1_kernel<<<12500, 256, 0, stream>>>(as_slab, rowstart, csr, x1);

    // conv2 s-half ONLY: s2 = x1 @ Wb2 (sortable); a2 computed in fused kernel
    mfma_gemm_nloop_kernel<64, 1><<<391, 256, 0, stream>>>(
        x1, Bt2 + 128 * 64, b2, 0, as_slab, NN);
    // fused conv2: a2 MFMA (global A-frags) + s2 gather-max -> x2
    ef128_a2_kernel<<<NN / 16, 256, 0, stream>>>(
        as_slab, x1, rowstart, csr, Bt2, b2, x2);

    // conv3 s-half ONLY: s3 = x2 @ Wb3 (sortable); a3 computed in fused kernel
    mfma_gemm_nloop_kernel<128, 4><<<391, 256, 0, stream>>>(
        x2, Bt3 + 512 * 128, b3, 0, as_slab, NN);

    // fused: a3 MFMA (global A-frags) + s3 gather-max + h=relu(X@W4+b4) + out += h@W5
    ef512_w5_kernel<<<NN / 16, 256, 0, stream>>>(
        as_slab, x2, rowstart, csr, Bt3, b3, W4t, b4, W5, out);
}